// Round 1
// baseline (124.950 us; speedup 1.0000x reference)
//
#include <hip/hip_runtime.h>

#define B_ 32
#define C_ 64
#define N_ 1024
#define T_ 64

typedef __attribute__((ext_vector_type(8))) _Float16 half8;   // 8 f16 = 4 VGPR
typedef __attribute__((ext_vector_type(4))) _Float16 half4;
typedef __attribute__((ext_vector_type(4))) float f32x4;

// ---------------------------------------------------------------------------
// K1: q = sum_c alpha[c]*x[b,c,:,:], stored as ONE fp16 plane. Pure stream,
// NT loads on x (read-once), 95% read ceiling (R8 probe) — do not touch.
// ---------------------------------------------------------------------------
__global__ __launch_bounds__(256) void k_q(const float* __restrict__ x,
                                           const float* __restrict__ alpha,
                                           _Float16* __restrict__ q_h) {
    const int bid = blockIdx.x;
    const int s1  = (bid & 7) * 256 + (bid >> 3);   // bijective, 2048%8==0
    const int b   = s1 >> 6;
    const int n0  = (s1 & 63) * 16;
    const int tid = threadIdx.x;

    const f32x4* xb = (const f32x4*)(x + (size_t)b * C_ * N_ * T_
                                       + (size_t)n0 * T_);
    f32x4 acc = {0.f, 0.f, 0.f, 0.f};
#pragma unroll 4
    for (int c = 0; c < C_; ++c) {
        f32x4 v = __builtin_nontemporal_load(&xb[(size_t)c * (N_ * T_ / 4) + tid]);
        const float ac = alpha[c];
        acc[0] += ac * v[0]; acc[1] += ac * v[1];
        acc[2] += ac * v[2]; acc[3] += ac * v[3];
    }

    half4 h;
#pragma unroll
    for (int j = 0; j < 4; ++j) h[j] = (_Float16)acc[j];   // RTNE cvt
    *(half4*)(q_h + ((size_t)b * N_ + n0) * T_ + (size_t)tid * 4) = h;
}

// ---------------------------------------------------------------------------
// K2 (R15): kill the LDS-issue-bound fp32 qw prologue.
//  - qw tile now computed by 4 MFMAs with SPLIT-PRECISION W:
//      W = W_hi(f16) + W_lo(f16 of residual); qw = q@W_hi + q@W_lo, f32 acc.
//    Matches the old f32-W VALU GEMM to ~2^-22 rel (q already f16 both ways).
//    A-frags read straight from q_h global (L2-hot) — qr staging deleted.
//  - Main-loop A-frags hoisted to registers once (af[2][2]) — removes
//    32 ds_read_b128/wave from the loop.
//  Theory: K2 was ~43us vs 20us write floor because ~15us of prologue LDS
//  issue + ~5us of loop LDS issue serialized per CU (NT->cached store change
//  was neutral => stores weren't binding). Predict K2 ~29us, total ~110us.
// ---------------------------------------------------------------------------
__global__ __launch_bounds__(512, 4) void k_scores_softmax(
        const _Float16* __restrict__ q_h,
        const float* __restrict__ W,
        float* __restrict__ out) {
    const int bid = blockIdx.x;
    const int s   = (bid & 7) * 128 + (bid >> 3);   // bijective, 1024%8==0
    const int b   = s >> 5;
    const int n0  = (s & 31) * 32;
    const int tid  = threadIdx.x;
    const int w    = tid >> 6;                      // wave 0..7 -> cols w*128
    const int lane = tid & 63;
    const int lr   = lane & 15;
    const int lk   = lane >> 4;

    __shared__ float Ws[T_][T_];                    // 16 KB fp32 W
    __shared__ _Float16 qwh[32][72];                // 4.5 KB f16 qw tile
    __shared__ float red[32][8];                    // 1 KB

    // ---- stage W (fp32, coalesced — proven pattern) ----
    {
        const f32x4* Wv = (const f32x4*)W;
        f32x4* Wd = (f32x4*)&Ws[0][0];
        Wd[tid]       = Wv[tid];
        Wd[tid + 512] = Wv[tid + 512];
    }
    __syncthreads();

    // ---- qw tile = q @ W via MFMA, split-precision W (hi+lo f16) ----
    // wave w computes 16x16 tile (tr = w>>2 row-block, tc = w&3 col-block)
    {
        const int tr = w >> 2, tc = w & 3;
        const size_t ar = ((size_t)b * N_ + n0 + tr * 16 + lr) * T_ + lk * 8;
        half8 a0 = *(const half8*)(q_h + ar);        // k = lk*8 .. +7
        half8 a1 = *(const half8*)(q_h + ar + 32);   // k = 32+lk*8 .. +7
        half8 bh0, bh1, bl0, bl1;
#pragma unroll
        for (int j = 0; j < 8; ++j) {
            const float wv0 = Ws[lk * 8 + j][tc * 16 + lr];
            const float wv1 = Ws[lk * 8 + 32 + j][tc * 16 + lr];
            const _Float16 h0 = (_Float16)wv0;
            const _Float16 h1 = (_Float16)wv1;
            bh0[j] = h0; bl0[j] = (_Float16)(wv0 - (float)h0);
            bh1[j] = h1; bl1[j] = (_Float16)(wv1 - (float)h1);
        }
        f32x4 a = {0.f, 0.f, 0.f, 0.f};
        a = __builtin_amdgcn_mfma_f32_16x16x32_f16(a0, bh0, a, 0, 0, 0);
        a = __builtin_amdgcn_mfma_f32_16x16x32_f16(a1, bh1, a, 0, 0, 0);
        a = __builtin_amdgcn_mfma_f32_16x16x32_f16(a0, bl0, a, 0, 0, 0);
        a = __builtin_amdgcn_mfma_f32_16x16x32_f16(a1, bl1, a, 0, 0, 0);
        // C layout: col = lr, row = lk*4 + r
#pragma unroll
        for (int r = 0; r < 4; ++r)
            qwh[tr * 16 + lk * 4 + r][tc * 16 + lr] = (_Float16)a[r];
    }
    __syncthreads();

    // ---- hoist A-frags to registers ONCE (was 32 ds_read_b128/wave) ----
    half8 af[2][2];
#pragma unroll
    for (int g = 0; g < 2; ++g) {
        af[g][0] = *(const half8*)&qwh[g * 16 + lr][lk * 8];
        af[g][1] = *(const half8*)&qwh[g * 16 + lr][lk * 8 + 32];
    }

    // ---- main MFMA loop: 2 f16 MFMAs/tile, 2-deep B prefetch ----
    f32x4 acc[2][8];
#pragma unroll
    for (int g = 0; g < 2; ++g)
#pragma unroll
        for (int cf = 0; cf < 8; ++cf) acc[g][cf] = {0.f, 0.f, 0.f, 0.f};

    const size_t cb0 = ((size_t)b * N_ + w * 128 + lr) * T_ + lk * 8;
    half8 pb0 = *(const half8*)(q_h + cb0);
    half8 pb1 = *(const half8*)(q_h + cb0 + 32);
#pragma unroll
    for (int cf = 0; cf < 8; ++cf) {
        const half8 bh0 = pb0;
        const half8 bh1 = pb1;
        if (cf < 7) {
            const size_t cbn = cb0 + (size_t)(cf + 1) * 16 * T_;
            pb0 = *(const half8*)(q_h + cbn);
            pb1 = *(const half8*)(q_h + cbn + 32);
        }
#pragma unroll
        for (int g = 0; g < 2; ++g) {
            f32x4 a = acc[g][cf];
            a = __builtin_amdgcn_mfma_f32_16x16x32_f16(af[g][0], bh0, a, 0, 0, 0);
            a = __builtin_amdgcn_mfma_f32_16x16x32_f16(af[g][1], bh1, a, 0, 0, 0);
            acc[g][cf] = a;
        }
    }

    // ---- max-free softmax epilogue, ONE barrier ----
    // acc[g][cf][r] = score[n0 + g*16 + lk*4 + r][w*128 + cf*16 + lr]
    float sv[2][4];
#pragma unroll
    for (int g = 0; g < 2; ++g) {
#pragma unroll
        for (int r = 0; r < 4; ++r) {
            float ssum = 0.f;
#pragma unroll
            for (int cf = 0; cf < 8; ++cf) {
                float e = __expf(acc[g][cf][r]);
                acc[g][cf][r] = e;
                ssum += e;
            }
            ssum += __shfl_xor(ssum, 1);
            ssum += __shfl_xor(ssum, 2);
            ssum += __shfl_xor(ssum, 4);
            ssum += __shfl_xor(ssum, 8);
            sv[g][r] = ssum;
        }
        if (lr == 0) {
#pragma unroll
            for (int r = 0; r < 4; ++r) red[g * 16 + lk * 4 + r][w] = sv[g][r];
        }
    }
    __syncthreads();

#pragma unroll
    for (int g = 0; g < 2; ++g) {
#pragma unroll
        for (int r = 0; r < 4; ++r) {
            f32x4 p0 = *(f32x4*)&red[g * 16 + lk * 4 + r][0];
            f32x4 p1 = *(f32x4*)&red[g * 16 + lk * 4 + r][4];
            const float inv = 1.0f / (p0[0] + p0[1] + p0[2] + p0[3] +
                                      p1[0] + p1[1] + p1[2] + p1[3]);
            float* orow = out + ((size_t)b * N_ + n0 + g * 16 + lk * 4 + r) * N_
                              + w * 128 + lr;
#pragma unroll
            for (int cf = 0; cf < 8; ++cf)
                orow[cf * 16] = acc[g][cf][r] * inv;   // cached store
        }
    }
}

// ---------------------------------------------------------------------------
extern "C" void kernel_launch(void* const* d_in, const int* in_sizes, int n_in,
                              void* d_out, int out_size, void* d_ws, size_t ws_size,
                              hipStream_t stream) {
    const float* x     = (const float*)d_in[0];
    const float* W     = (const float*)d_in[1];
    const float* alpha = (const float*)d_in[2];
    float* out = (float*)d_out;

    _Float16* q_h = (_Float16*)d_ws;                // [B,N,T] f16, 4 MB

    k_q<<<2048, 256, 0, stream>>>(x, alpha, q_h);
    k_scores_softmax<<<1024, 512, 0, stream>>>(q_h, W, out);
}